// Round 13
// baseline (52.784 us; speedup 1.0000x reference)
//
#include <hip/hip_runtime.h>

// Problem constants (fixed by the reference harness).
constexpr int Nn   = 100000;   // nodes
constexpr int Ee   = 1600000;  // edges  (divisible by 4)
constexpr int D    = 128;      // feature dim
constexpr int NT   = 18;       // 2 + 16 target entries (duplicates allowed)

// Capacities (expected: |L2|~290, |S|~310, conv1 hit edges ~5600)
constexpr int CAPS = 1024;
constexpr int CAP2 = 1024;

constexpr int BMW  = 3136;     // bitmap words: >= ceil(Nn/32)=3125, %4==0
constexpr int LOCT = 64;       // scanT per-block staging (expected ~0.6 hits)
constexpr int LOCS = 128;      // scanS per-block staging (expected ~11 hits)
constexpr int MAXM = 96;       // per-target matched-edge cap (mean ~16)

// hdr slots
#define HDR_CNTS  1
#define HDR_CNTL2 3

// ---- workspace byte offsets (all 16B aligned) ----
// [0, 12800) = hdr + bmS, zeroed by k_zero0 (NOT hipMemsetAsync — the rocclr
// small-fill blit costs ~40 µs fixed; a 4-block kernel is ~2 µs).
// A1 is zeroed inside k_scanT (ordered before k_scanSA by the boundary).
// markS is never zeroed — only read at entries the current call wrote
// (bmS-bitmap-guarded).
constexpr size_t OFF_HDR   = 0;          // int[64]          256
constexpr size_t OFF_BMS   = 256;        // u32[BMW]         12544
constexpr size_t ZERO0_B   = 12800;      // hdr + bmS
constexpr size_t OFF_A1    = 12800;      // f32[CAPS*D]      524288
constexpr size_t OFF_MARKS = 537088;     // int[Nn]          400000  (dirty ok)
constexpr size_t OFF_SLIST = 937088;     // int[CAPS]        4096
constexpr size_t OFF_L2    = 941184;     // int[CAP2*3]      12288
constexpr size_t OFF_HS    = 953472;     // f32[CAPS*D]      524288
constexpr size_t WS_NEED   = 1477760;

// Tiny zero kernel for hdr + bmS (800 uint4).
__global__ void __launch_bounds__(256)
k_zero0(uint4* p) {
    int i = blockIdx.x * blockDim.x + threadIdx.x;
    if (i < (int)(ZERO0_B / 16)) p[i] = uint4{0u, 0u, 0u, 0u};
}

// Claim node v into the compact S set. Uniqueness comes from the atomicOr on
// the (zeroed) S-bitmap: the thread whose Or first sets the bit is the unique
// claimer and writes Slist + markS (markS needs no zero-init — readers are
// bitmap-guarded). ~310 claims total, spread addresses -> no contention.
__device__ __forceinline__ void claim_node(int v, int* markS, int* hdr,
                                           int* Slist, unsigned* bmS) {
    unsigned bit = 1u << (v & 31);
    unsigned old = atomicOr(&bmS[(unsigned)v >> 5], bit);
    if (!(old & bit)) {
        int s = atomicAdd(&hdr[HDR_CNTS], 1);
        if (s < CAPS) { Slist[s] = v; markS[v] = 2 + s; }
    }
}

// Scan all edges; per-block LDS bitmap of the 18 target ids. Hits recorded
// into L2 (LDS-staged, one reservation atomic per block) and their sources
// claimed into S inline. Block 0 claims the targets too. Also zeroes A1
// (consumed by the NEXT kernel — boundary orders it).
__global__ void __launch_bounds__(256)
k_scanT(const int* __restrict__ src, const int* __restrict__ dst,
        const int* __restrict__ cur, const int* __restrict__ des,
        const int* __restrict__ nbr,
        int* __restrict__ hdr, int* __restrict__ markS,
        unsigned* __restrict__ bmS, int* __restrict__ Slist,
        int* __restrict__ L2, float4* __restrict__ A1z) {
    __shared__ unsigned bm[BMW];
    __shared__ int sT[NT];
    __shared__ int loc[LOCT * 3];
    __shared__ int lcnt, lbase;
    int t = threadIdx.x;
    int gtid = blockIdx.x * blockDim.x + t;
    int gstride = gridDim.x * blockDim.x;
    // zero A1 for k_scanSA (524288 B = 32768 float4)
    for (int i = gtid; i < 32768; i += gstride) A1z[i] = float4{0.f, 0.f, 0.f, 0.f};
    if (t == 0) lcnt = 0;
    for (int w = t; w < BMW / 4; w += 256)
        reinterpret_cast<uint4*>(bm)[w] = uint4{0u, 0u, 0u, 0u};
    if (t < NT) sT[t] = (t == 0) ? cur[0] : (t == 1) ? des[0] : nbr[t - 2];
    __syncthreads();
    if (t < NT) {
        int v = sT[t];
        atomicOr(&bm[(unsigned)v >> 5], 1u << (v & 31));
        if (blockIdx.x == 0) claim_node(v, markS, hdr, Slist, bmS);  // targets need h
    }
    __syncthreads();
    for (int q = gtid; q < Ee / 4; q += gstride) {
        int4 d4 = reinterpret_cast<const int4*>(dst)[q];
        int dsv[4] = {d4.x, d4.y, d4.z, d4.w};
        #pragma unroll
        for (int j = 0; j < 4; ++j) {
            int d = dsv[j];
            if ((bm[(unsigned)d >> 5] >> (d & 31)) & 1u) {
                int slot = 0;
                while (sT[slot] != d) ++slot;   // first occurrence, always found
                int e = q * 4 + j;
                int s = src[e];
                claim_node(s, markS, hdr, Slist, bmS);
                int li = atomicAdd(&lcnt, 1);
                if (li < LOCT) {
                    loc[3*li] = s; loc[3*li+1] = e; loc[3*li+2] = slot;
                } else {  // overflow fallback (statistically never)
                    int idx = atomicAdd(&hdr[HDR_CNTL2], 1);
                    if (idx < CAP2) { L2[3*idx] = s; L2[3*idx+1] = e; L2[3*idx+2] = slot; }
                }
            }
        }
    }
    __syncthreads();
    if (t == 0) {
        int n = lcnt < LOCT ? lcnt : LOCT;
        lcnt = n;
        if (n) lbase = atomicAdd(&hdr[HDR_CNTL2], n);
    }
    __syncthreads();
    for (int i = t; i < lcnt; i += 256) {
        int idx = lbase + i;
        if (idx < CAP2) {
            L2[3*idx] = loc[3*i]; L2[3*idx+1] = loc[3*i+1]; L2[3*idx+2] = loc[3*i+2];
        }
    }
}

// Scan all edges; membership test against LDS copy of S-bitmap; staged hits
// are aggregated cooperatively into A1 at the end (no edge list).
// A1[slot][d] += relu(x[src][d] + ea[e]*We1[d] + be1[d])
__global__ void __launch_bounds__(256)
k_scanSA(const float* __restrict__ x, const int* __restrict__ src,
         const int* __restrict__ dst, const float* __restrict__ ea,
         const float* __restrict__ We1, const float* __restrict__ be1,
         const int* __restrict__ markS, const unsigned* __restrict__ bmS,
         float* __restrict__ A1) {
    __shared__ unsigned bm[BMW];
    __shared__ int loc[LOCS * 3];
    __shared__ int lcnt;
    int t = threadIdx.x;
    if (t == 0) lcnt = 0;
    const uint4* g4 = reinterpret_cast<const uint4*>(bmS);
    for (int w = t; w < BMW / 4; w += 256) reinterpret_cast<uint4*>(bm)[w] = g4[w];
    __syncthreads();
    int stride = gridDim.x * blockDim.x;
    for (int q = blockIdx.x * blockDim.x + t; q < Ee / 4; q += stride) {
        int4 d4 = reinterpret_cast<const int4*>(dst)[q];
        int dsv[4] = {d4.x, d4.y, d4.z, d4.w};
        #pragma unroll
        for (int j = 0; j < 4; ++j) {
            int d = dsv[j];
            if ((bm[(unsigned)d >> 5] >> (d & 31)) & 1u) {
                int v = markS[d];
                if (v >= 2 && (unsigned)(v - 2) < (unsigned)CAPS) {
                    int e = q * 4 + j;
                    int li = atomicAdd(&lcnt, 1);
                    if (li < LOCS) {
                        loc[3*li] = src[e]; loc[3*li+1] = e; loc[3*li+2] = v - 2;
                    } else {  // inline slow path (statistically never)
                        float a = ea[e];
                        int s = src[e];
                        for (int d0 = 0; d0 < D; ++d0)
                            atomicAdd(&A1[(size_t)(v - 2) * D + d0],
                                      fmaxf(fmaf(a, We1[d0], be1[d0]) + x[(size_t)s * D + d0], 0.f));
                    }
                }
            }
        }
    }
    __syncthreads();
    int n = lcnt < LOCS ? lcnt : LOCS;
    int w = t >> 6, l = t & 63;          // 4 waves; lane handles 2 dims
    int d0 = l * 2;
    for (int i = w; i < n; i += 4) {
        int s = loc[3*i], e = loc[3*i+1], slot = loc[3*i+2];
        float a = ea[e];
        float2 xv = *reinterpret_cast<const float2*>(&x[(size_t)s * D + d0]);
        float2 wv = *reinterpret_cast<const float2*>(&We1[d0]);
        float2 bv = *reinterpret_cast<const float2*>(&be1[d0]);
        atomicAdd(&A1[(size_t)slot * D + d0],     fmaxf(fmaf(a, wv.x, bv.x) + xv.x, 0.f));
        atomicAdd(&A1[(size_t)slot * D + d0 + 1], fmaxf(fmaf(a, wv.y, bv.y) + xv.y, 0.f));
    }
}

// conv1 MLP per S-node (grid-stride), 2-way K-split (chain 128 -> 64):
// Hs[b] = relu( relu((x[node]+A1[b])@W1 + b1) @ W2 + b2 )
__global__ void __launch_bounds__(256)
k_mlpS(const float* __restrict__ x, const float* __restrict__ A,
       const int* __restrict__ Slist, const int* __restrict__ hdr,
       const float* __restrict__ W1, const float* __restrict__ b1,
       const float* __restrict__ W2, const float* __restrict__ b2,
       float* __restrict__ Hs) {
    __shared__ float buf[D];
    __shared__ float hid[D];
    __shared__ float part[2][D];
    int cnt = hdr[HDR_CNTS];
    if (cnt > CAPS) cnt = CAPS;
    int tid = threadIdx.x;        // 256
    int t = tid & 127, g = tid >> 7;   // out-dim, K-half
    for (int b = blockIdx.x; b < cnt; b += gridDim.x) {
        if (g == 0) {
            int node = Slist[b];
            buf[t] = x[(size_t)node * D + t] + A[(size_t)b * D + t];
        }
        __syncthreads();
        float acc = 0.f;
        int c0 = g * 64;
        #pragma unroll 8
        for (int c = c0; c < c0 + 64; ++c) acc = fmaf(buf[c], W1[c * D + t], acc);
        part[g][t] = acc;
        __syncthreads();
        if (g == 0) hid[t] = fmaxf(part[0][t] + part[1][t] + b1[t], 0.f);
        __syncthreads();
        acc = 0.f;
        #pragma unroll 8
        for (int c = c0; c < c0 + 64; ++c) acc = fmaf(hid[c], W2[c * D + t], acc);
        part[g][t] = acc;
        __syncthreads();
        if (g == 0) Hs[(size_t)b * D + t] = fmaxf(part[0][t] + part[1][t] + b2[t], 0.f);
        __syncthreads();
    }
}

// Fused tail: block k (0..15) computes the three embeddings it needs
// (curr, dest, nbr_k; curr/dest redundantly across blocks) with the proven
// 512-thread 4-way K-split recipe (chains <= 32), then the policy head.
__global__ void __launch_bounds__(512)
k_tail2(const float* __restrict__ Hs, const int* __restrict__ L2,
        const int* __restrict__ hdr, const int* __restrict__ markS,
        const int* __restrict__ cur, const int* __restrict__ des,
        const int* __restrict__ nbr, const float* __restrict__ ea,
        const float* __restrict__ We2, const float* __restrict__ be2,
        const float* __restrict__ W21, const float* __restrict__ b21,
        const float* __restrict__ W22, const float* __restrict__ b22,
        const float* __restrict__ Wl1, const float* __restrict__ bl1,
        const float* __restrict__ Wl2, const float* __restrict__ bl2,
        float* __restrict__ out) {
    __shared__ int sT[NT];
    __shared__ float buf[3][D];
    __shared__ float hid[3][D];
    __shared__ float emb[3][D];
    __shared__ float part[4][D];
    __shared__ float red[D];
    __shared__ int   mss[3][MAXM];
    __shared__ float mea[3][MAXM];
    __shared__ int   mcnt[3];
    int tid = threadIdx.x;   // 512 = 8 waves
    int k = blockIdx.x;      // 0..15
    if (tid < NT) sT[tid] = (tid == 0) ? cur[0] : (tid == 1) ? des[0] : nbr[tid - 2];
    if (tid < 3) mcnt[tid] = 0;
    __syncthreads();
    // first-occurrence slots (must match k_scanT semantics)
    int dsl = (sT[1] == sT[0]) ? 0 : 1;
    int nn = sT[2 + k];
    int nsl = 2 + k;
    for (int j = 0; j < 2 + k; ++j) if (sT[j] == nn) { nsl = j; break; }
    const int rs[3] = {0, dsl, nsl};
    // filter L2 into the 3 role lists (L2 slots are first-occurrence slots)
    int cnt2 = hdr[HDR_CNTL2]; if (cnt2 > CAP2) cnt2 = CAP2;
    for (int i = tid; i < cnt2; i += 512) {
        int slot = L2[3*i + 2];
        bool m0 = (slot == rs[0]), m1 = (slot == rs[1]), m2 = (slot == rs[2]);
        if (m0 | m1 | m2) {
            int sm = markS[L2[3*i]] - 2;
            float av = ea[L2[3*i + 1]];
            if (m0) { int li = atomicAdd(&mcnt[0], 1); if (li < MAXM) { mss[0][li] = sm; mea[0][li] = av; } }
            if (m1) { int li = atomicAdd(&mcnt[1], 1); if (li < MAXM) { mss[1][li] = sm; mea[1][li] = av; } }
            if (m2) { int li = atomicAdd(&mcnt[2], 1); if (li < MAXM) { mss[2][li] = sm; mea[2][li] = av; } }
        }
    }
    __syncthreads();
    int t = tid & 127, g = tid >> 7;   // out-dim, K-group (4)
    float w2 = We2[t], bb2 = be2[t];
    // conv2 aggregation + self term, per role (4-way edge split)
    #pragma unroll
    for (int r = 0; r < 3; ++r) {
        int n = mcnt[r] < MAXM ? mcnt[r] : MAXM;
        float a = 0.f;
        for (int i = g; i < n; i += 4) {
            int ss = mss[r][i];
            if ((unsigned)ss < (unsigned)CAPS)
                a += fmaxf(fmaf(mea[r][i], w2, bb2) + Hs[(size_t)ss * D + t], 0.f);
        }
        part[g][t] = a;
        __syncthreads();
        if (g == 0) {
            int sst = markS[sT[rs[r]]] - 2;
            float self = ((unsigned)sst < (unsigned)CAPS) ? Hs[(size_t)sst * D + t] : 0.f;
            buf[r][t] = self + part[0][t] + part[1][t] + part[2][t] + part[3][t];
        }
        __syncthreads();
    }
    // conv2 MLP layer 1 (K-chunks of 32)
    int c0 = g * 32;
    #pragma unroll
    for (int r = 0; r < 3; ++r) {
        float acc = 0.f;
        #pragma unroll 8
        for (int c = c0; c < c0 + 32; ++c) acc = fmaf(buf[r][c], W21[c * D + t], acc);
        part[g][t] = acc;
        __syncthreads();
        if (g == 0) hid[r][t] = fmaxf(part[0][t] + part[1][t] + part[2][t] + part[3][t] + b21[t], 0.f);
        __syncthreads();
    }
    // layer 2
    #pragma unroll
    for (int r = 0; r < 3; ++r) {
        float acc = 0.f;
        #pragma unroll 8
        for (int c = c0; c < c0 + 32; ++c) acc = fmaf(hid[r][c], W22[c * D + t], acc);
        part[g][t] = acc;
        __syncthreads();
        if (g == 0) emb[r][t] = part[0][t] + part[1][t] + part[2][t] + part[3][t] + b22[t];  // no final relu
        __syncthreads();
    }
    // policy head: 4-way split of the 384-long dot (R5-proven structure)
    {
        float acc = 0.f;
        int p0 = g * 96;
        #pragma unroll 8
        for (int c = p0; c < p0 + 96; ++c)
            acc = fmaf(emb[c >> 7][c & 127], Wl1[c * D + t], acc);
        part[g][t] = acc;
        __syncthreads();
        if (tid < D) {
            float v = part[0][t] + part[1][t] + part[2][t] + part[3][t] + bl1[t];
            red[t] = fmaxf(v, 0.f) * Wl2[t];
        }
        __syncthreads();
        for (int s = 64; s > 0; s >>= 1) {
            if (tid < s) red[tid] += red[tid + s];
            __syncthreads();
        }
        if (tid == 0) out[k] = red[0] + bl2[0];
    }
}

extern "C" void kernel_launch(void* const* d_in, const int* in_sizes, int n_in,
                              void* d_out, int out_size, void* d_ws, size_t ws_size,
                              hipStream_t stream) {
    if (ws_size < WS_NEED) return;  // safety guard

    const float* x   = (const float*)d_in[0];
    const int*   ei  = (const int*)d_in[1];   // (2,E) row-major int32
    const int*   cur = (const int*)d_in[2];
    const int*   des = (const int*)d_in[3];
    const int*   nbr = (const int*)d_in[4];
    const float* ea  = (const float*)d_in[5]; // (E,1)
    const float* We1 = (const float*)d_in[6];
    const float* be1 = (const float*)d_in[7];
    const float* W11 = (const float*)d_in[8];
    const float* b11 = (const float*)d_in[9];
    const float* W12 = (const float*)d_in[10];
    const float* b12 = (const float*)d_in[11];
    const float* We2 = (const float*)d_in[12];
    const float* be2 = (const float*)d_in[13];
    const float* W21 = (const float*)d_in[14];
    const float* b21 = (const float*)d_in[15];
    const float* W22 = (const float*)d_in[16];
    const float* b22 = (const float*)d_in[17];
    const float* Wl1 = (const float*)d_in[18];
    const float* bl1 = (const float*)d_in[19];
    const float* Wl2 = (const float*)d_in[20];
    const float* bl2 = (const float*)d_in[21];
    float* out = (float*)d_out;

    char*     ws    = (char*)d_ws;
    int*      hdr   = (int*)(ws + OFF_HDR);
    unsigned* bmS   = (unsigned*)(ws + OFF_BMS);
    float*    A1    = (float*)(ws + OFF_A1);
    int*      markS = (int*)(ws + OFF_MARKS);
    int*      Slist = (int*)(ws + OFF_SLIST);
    int*      L2    = (int*)(ws + OFF_L2);
    float*    Hs    = (float*)(ws + OFF_HS);

    const int* srcp = ei;
    const int* dstp = ei + Ee;

    k_zero0 <<<4, 256, 0, stream>>>((uint4*)ws);          // hdr + bmS (12.8 KB)
    k_scanT <<<512, 256, 0, stream>>>(srcp, dstp, cur, des, nbr,
                                      hdr, markS, bmS, Slist, L2, (float4*)A1);
    k_scanSA<<<512, 256, 0, stream>>>(x, srcp, dstp, ea, We1, be1,
                                      markS, bmS, A1);
    k_mlpS  <<<320, 256, 0, stream>>>(x, A1, Slist, hdr, W11, b11, W12, b12, Hs);
    k_tail2 <<<16, 512, 0, stream>>>(Hs, L2, hdr, markS, cur, des, nbr, ea,
                                     We2, be2, W21, b21, W22, b22,
                                     Wl1, bl1, Wl2, bl2, out);
}

// Round 14
// 47.349 us; speedup vs baseline: 1.1148x; 1.1148x over previous
//
#include <hip/hip_runtime.h>

// Problem constants (fixed by the reference harness).
constexpr int Nn   = 100000;   // nodes
constexpr int Ee   = 1600000;  // edges  (divisible by 4)
constexpr int D    = 128;      // feature dim
constexpr int NT   = 18;       // 2 + 16 target entries (duplicates allowed)

// Capacities (expected: |L2|~290, |S|~310, conv1 hit edges ~5600)
constexpr int CAPS = 1024;
constexpr int CAP2 = 1024;

constexpr int BMW  = 3136;     // bitmap words: >= ceil(Nn/32)=3125, %4==0
constexpr int LOCT = 64;       // scanT per-block staging (expected ~0.6 hits)
constexpr int LOCS = 128;      // scanS per-block staging (expected ~11 hits)
constexpr int MAXM = 96;       // per-target matched-edge cap (mean ~16)

// hdr slots
#define HDR_CNTS  1
#define HDR_CNTL2 3

// ---- workspace byte offsets (all 16B aligned) ----
// Zeroed region first (hdr + bmS + A1) via k_zero (NOT hipMemsetAsync — the
// rocclr small-fill blit has ~40 µs fixed cost). markS is never zeroed — it
// is only read at entries the current call wrote (bmS-bitmap-guarded).
constexpr size_t OFF_HDR   = 0;          // int[64]          256
constexpr size_t OFF_BMS   = 256;        // u32[BMW]         12544
constexpr size_t OFF_A1    = 12800;      // f32[CAPS*D]      524288
constexpr size_t ZERO_BYTES= 537088;     // zero everything above (÷16 ok)
constexpr size_t OFF_MARKS = 537088;     // int[Nn]          400000  (dirty ok)
constexpr size_t OFF_SLIST = 937088;     // int[CAPS]        4096
constexpr size_t OFF_L2    = 941184;     // int[CAP2*3]      12288
constexpr size_t OFF_HS    = 953472;     // f32[CAPS*D]      524288
constexpr size_t OFF_EMB   = 1477760;    // f32[NT*D]        9216
constexpr size_t WS_NEED   = 1486976;

__global__ void k_zero(float4* p, int n4) {
    int i = blockIdx.x * blockDim.x + threadIdx.x;
    int stride = gridDim.x * blockDim.x;
    for (; i < n4; i += stride) p[i] = float4{0.f, 0.f, 0.f, 0.f};
}

// Claim node v into the compact S set. Uniqueness comes from the atomicOr on
// the (zeroed) S-bitmap: the thread whose Or first sets the bit is the unique
// claimer and writes Slist + markS (markS needs no zero-init — readers are
// bitmap-guarded). ~310 claims total, spread addresses -> no contention.
__device__ __forceinline__ void claim_node(int v, int* markS, int* hdr,
                                           int* Slist, unsigned* bmS) {
    unsigned bit = 1u << (v & 31);
    unsigned old = atomicOr(&bmS[(unsigned)v >> 5], bit);
    if (!(old & bit)) {
        int s = atomicAdd(&hdr[HDR_CNTS], 1);
        if (s < CAPS) { Slist[s] = v; markS[v] = 2 + s; }
    }
}

// Scan all edges; per-block LDS bitmap of the 18 target ids. Hits recorded
// into L2 (LDS-staged, one reservation atomic per block) and their sources
// claimed into S inline. Block 0 claims the targets too.
__global__ void __launch_bounds__(256)
k_scanT(const int* __restrict__ src, const int* __restrict__ dst,
        const int* __restrict__ cur, const int* __restrict__ des,
        const int* __restrict__ nbr,
        int* __restrict__ hdr, int* __restrict__ markS,
        unsigned* __restrict__ bmS, int* __restrict__ Slist,
        int* __restrict__ L2) {
    __shared__ unsigned bm[BMW];
    __shared__ int sT[NT];
    __shared__ int loc[LOCT * 3];
    __shared__ int lcnt, lbase;
    int t = threadIdx.x;
    if (t == 0) lcnt = 0;
    for (int w = t; w < BMW / 4; w += 256)
        reinterpret_cast<uint4*>(bm)[w] = uint4{0u, 0u, 0u, 0u};
    if (t < NT) sT[t] = (t == 0) ? cur[0] : (t == 1) ? des[0] : nbr[t - 2];
    __syncthreads();
    if (t < NT) {
        int v = sT[t];
        atomicOr(&bm[(unsigned)v >> 5], 1u << (v & 31));
        if (blockIdx.x == 0) claim_node(v, markS, hdr, Slist, bmS);  // targets need h
    }
    __syncthreads();
    int stride = gridDim.x * blockDim.x;
    for (int q = blockIdx.x * blockDim.x + t; q < Ee / 4; q += stride) {
        int4 d4 = reinterpret_cast<const int4*>(dst)[q];
        int dsv[4] = {d4.x, d4.y, d4.z, d4.w};
        #pragma unroll
        for (int j = 0; j < 4; ++j) {
            int d = dsv[j];
            if ((bm[(unsigned)d >> 5] >> (d & 31)) & 1u) {
                int slot = 0;
                while (sT[slot] != d) ++slot;   // first occurrence, always found
                int e = q * 4 + j;
                int s = src[e];
                claim_node(s, markS, hdr, Slist, bmS);
                int li = atomicAdd(&lcnt, 1);
                if (li < LOCT) {
                    loc[3*li] = s; loc[3*li+1] = e; loc[3*li+2] = slot;
                } else {  // overflow fallback (statistically never)
                    int idx = atomicAdd(&hdr[HDR_CNTL2], 1);
                    if (idx < CAP2) { L2[3*idx] = s; L2[3*idx+1] = e; L2[3*idx+2] = slot; }
                }
            }
        }
    }
    __syncthreads();
    if (t == 0) {
        int n = lcnt < LOCT ? lcnt : LOCT;
        lcnt = n;
        if (n) lbase = atomicAdd(&hdr[HDR_CNTL2], n);
    }
    __syncthreads();
    for (int i = t; i < lcnt; i += 256) {
        int idx = lbase + i;
        if (idx < CAP2) {
            L2[3*idx] = loc[3*i]; L2[3*idx+1] = loc[3*i+1]; L2[3*idx+2] = loc[3*i+2];
        }
    }
}

// Scan all edges; membership test against LDS copy of S-bitmap; staged hits
// are aggregated cooperatively into A1 at the end (no edge list).
// A1[slot][d] += relu(x[src][d] + ea[e]*We1[d] + be1[d])
__global__ void __launch_bounds__(256)
k_scanSA(const float* __restrict__ x, const int* __restrict__ src,
         const int* __restrict__ dst, const float* __restrict__ ea,
         const float* __restrict__ We1, const float* __restrict__ be1,
         const int* __restrict__ markS, const unsigned* __restrict__ bmS,
         float* __restrict__ A1) {
    __shared__ unsigned bm[BMW];
    __shared__ int loc[LOCS * 3];
    __shared__ int lcnt;
    int t = threadIdx.x;
    if (t == 0) lcnt = 0;
    const uint4* g4 = reinterpret_cast<const uint4*>(bmS);
    for (int w = t; w < BMW / 4; w += 256) reinterpret_cast<uint4*>(bm)[w] = g4[w];
    __syncthreads();
    int stride = gridDim.x * blockDim.x;
    for (int q = blockIdx.x * blockDim.x + t; q < Ee / 4; q += stride) {
        int4 d4 = reinterpret_cast<const int4*>(dst)[q];
        int dsv[4] = {d4.x, d4.y, d4.z, d4.w};
        #pragma unroll
        for (int j = 0; j < 4; ++j) {
            int d = dsv[j];
            if ((bm[(unsigned)d >> 5] >> (d & 31)) & 1u) {
                int v = markS[d];
                if (v >= 2 && (unsigned)(v - 2) < (unsigned)CAPS) {
                    int e = q * 4 + j;
                    int li = atomicAdd(&lcnt, 1);
                    if (li < LOCS) {
                        loc[3*li] = src[e]; loc[3*li+1] = e; loc[3*li+2] = v - 2;
                    } else {  // inline slow path (statistically never)
                        float a = ea[e];
                        int s = src[e];
                        for (int d0 = 0; d0 < D; ++d0)
                            atomicAdd(&A1[(size_t)(v - 2) * D + d0],
                                      fmaxf(fmaf(a, We1[d0], be1[d0]) + x[(size_t)s * D + d0], 0.f));
                    }
                }
            }
        }
    }
    __syncthreads();
    int n = lcnt < LOCS ? lcnt : LOCS;
    int w = t >> 6, l = t & 63;          // 4 waves; lane handles 2 dims
    int d0 = l * 2;
    for (int i = w; i < n; i += 4) {
        int s = loc[3*i], e = loc[3*i+1], slot = loc[3*i+2];
        float a = ea[e];
        float2 xv = *reinterpret_cast<const float2*>(&x[(size_t)s * D + d0]);
        float2 wv = *reinterpret_cast<const float2*>(&We1[d0]);
        float2 bv = *reinterpret_cast<const float2*>(&be1[d0]);
        atomicAdd(&A1[(size_t)slot * D + d0],     fmaxf(fmaf(a, wv.x, bv.x) + xv.x, 0.f));
        atomicAdd(&A1[(size_t)slot * D + d0 + 1], fmaxf(fmaf(a, wv.y, bv.y) + xv.y, 0.f));
    }
}

// conv1 MLP per S-node (grid-stride), 4-way K-split (chain 128 -> 32):
// Hs[b] = relu( relu((x[node]+A1[b])@W1 + b1) @ W2 + b2 )
__global__ void __launch_bounds__(512)
k_mlpS(const float* __restrict__ x, const float* __restrict__ A,
       const int* __restrict__ Slist, const int* __restrict__ hdr,
       const float* __restrict__ W1, const float* __restrict__ b1,
       const float* __restrict__ W2, const float* __restrict__ b2,
       float* __restrict__ Hs) {
    __shared__ float buf[D];
    __shared__ float hid[D];
    __shared__ float part[4][D];
    int cnt = hdr[HDR_CNTS];
    if (cnt > CAPS) cnt = CAPS;
    int tid = threadIdx.x;             // 512 = 8 waves
    int t = tid & 127, g = tid >> 7;   // out-dim, K-quarter
    int c0 = g * 32;
    for (int b = blockIdx.x; b < cnt; b += gridDim.x) {
        if (g == 0) {
            int node = Slist[b];
            buf[t] = x[(size_t)node * D + t] + A[(size_t)b * D + t];
        }
        __syncthreads();
        float acc = 0.f;
        #pragma unroll 8
        for (int c = c0; c < c0 + 32; ++c) acc = fmaf(buf[c], W1[c * D + t], acc);
        part[g][t] = acc;
        __syncthreads();
        if (g == 0)
            hid[t] = fmaxf(part[0][t] + part[1][t] + part[2][t] + part[3][t] + b1[t], 0.f);
        __syncthreads();
        acc = 0.f;
        #pragma unroll 8
        for (int c = c0; c < c0 + 32; ++c) acc = fmaf(hid[c], W2[c * D + t], acc);
        part[g][t] = acc;
        __syncthreads();
        if (g == 0)
            Hs[(size_t)b * D + t] =
                fmaxf(part[0][t] + part[1][t] + part[2][t] + part[3][t] + b2[t], 0.f);
        __syncthreads();
    }
}

// Per-target tail, 4-way K-split: block b filters the ~290 L2 edges for
// slot==b, aggregates conv2 messages (4-way edge split), then the conv2 MLP
// with 32-long K-chunks -> EMB[b]. 18 blocks x 512 threads (8 waves).
__global__ void __launch_bounds__(512)
k_tailT(const float* __restrict__ Hs, const int* __restrict__ L2,
        const int* __restrict__ hdr, const int* __restrict__ markS,
        const int* __restrict__ cur, const int* __restrict__ des,
        const int* __restrict__ nbr, const float* __restrict__ ea,
        const float* __restrict__ We2, const float* __restrict__ be2,
        const float* __restrict__ W21, const float* __restrict__ b21,
        const float* __restrict__ W22, const float* __restrict__ b22,
        float* __restrict__ EMB) {
    __shared__ int sT[NT];
    __shared__ float buf[D];
    __shared__ float hid[D];
    __shared__ float part[4][D];
    __shared__ int mss[MAXM];
    __shared__ float mea[MAXM];
    __shared__ int mcnt;
    int tid = threadIdx.x;   // 512
    int b = blockIdx.x;      // 0..17
    if (tid == 0) mcnt = 0;
    if (tid < NT) sT[tid] = (tid == 0) ? cur[0] : (tid == 1) ? des[0] : nbr[tid - 2];
    __syncthreads();
    int node = sT[b];
    for (int j = 0; j < b; ++j) if (sT[j] == node) return;  // dup entry: skip
    int cnt2 = hdr[HDR_CNTL2]; if (cnt2 > CAP2) cnt2 = CAP2;
    for (int i = tid; i < cnt2; i += 512) {
        if (L2[3*i + 2] == b) {
            int li = atomicAdd(&mcnt, 1);
            if (li < MAXM) {
                mss[li] = markS[L2[3*i]] - 2;
                mea[li] = ea[L2[3*i + 1]];
            }
        }
    }
    __syncthreads();
    int n = mcnt < MAXM ? mcnt : MAXM;
    int t = tid & 127, g = tid >> 7;   // out-dim, K-group (4)
    // aggregation: 4-way edge split
    float w2 = We2[t], bb2 = be2[t];
    float a = 0.f;
    for (int i = g; i < n; i += 4) {
        int ss = mss[i];
        if ((unsigned)ss < (unsigned)CAPS)
            a += fmaxf(fmaf(mea[i], w2, bb2) + Hs[(size_t)ss * D + t], 0.f);
    }
    part[g][t] = a;
    __syncthreads();
    if (g == 0) {
        int sst = markS[node] - 2;
        float self = ((unsigned)sst < (unsigned)CAPS) ? Hs[(size_t)sst * D + t] : 0.f;
        buf[t] = self + part[0][t] + part[1][t] + part[2][t] + part[3][t];
    }
    __syncthreads();
    // MLP layer 1: K-chunks of 32
    float acc = 0.f;
    int c0 = g * 32;
    #pragma unroll 8
    for (int c = c0; c < c0 + 32; ++c) acc = fmaf(buf[c], W21[c * D + t], acc);
    part[g][t] = acc;
    __syncthreads();
    if (g == 0) hid[t] = fmaxf(part[0][t] + part[1][t] + part[2][t] + part[3][t] + b21[t], 0.f);
    __syncthreads();
    // layer 2
    acc = 0.f;
    #pragma unroll 8
    for (int c = c0; c < c0 + 32; ++c) acc = fmaf(hid[c], W22[c * D + t], acc);
    part[g][t] = acc;
    __syncthreads();
    if (g == 0)
        EMB[b * D + t] = part[0][t] + part[1][t] + part[2][t] + part[3][t] + b22[t];  // no final relu
}

// Policy head: one block per neighbor k; 512 threads = 4-way split of the
// 384-long dot product, LDS-reduced. (R5-proven.)
__global__ void __launch_bounds__(512)
k_policy(const float* __restrict__ EMB,
         const int* __restrict__ cur, const int* __restrict__ des,
         const int* __restrict__ nbr,
         const float* __restrict__ Wl1, const float* __restrict__ bl1,
         const float* __restrict__ Wl2, const float* __restrict__ bl2,
         float* __restrict__ out) {
    __shared__ int sT[NT];
    __shared__ float cat[3 * D];
    __shared__ float part[4][D];
    __shared__ float red[D];
    int tid = threadIdx.x;
    int k = blockIdx.x;  // 0..15
    if (tid < NT) sT[tid] = (tid == 0) ? cur[0] : (tid == 1) ? des[0] : nbr[tid - 2];
    __syncthreads();
    // first-occurrence slots (must match k_scanT / k_tailT semantics)
    int dsl = (sT[1] == sT[0]) ? 0 : 1;
    int nn = sT[2 + k];
    int nsl = 2 + k;
    for (int j = 0; j < 2 + k; ++j) if (sT[j] == nn) { nsl = j; break; }
    if (tid < 3 * D) {
        int seg = tid >> 7;             // 0=curr, 1=dest, 2=nbr
        int t = tid & (D - 1);
        int slot = (seg == 0) ? 0 : (seg == 1) ? dsl : nsl;
        cat[tid] = EMB[slot * D + t];
    }
    __syncthreads();
    int h = tid >> 7;        // 0..3
    int t = tid & (D - 1);
    float acc = 0.f;
    int c0 = h * 96;
    #pragma unroll 8
    for (int c = c0; c < c0 + 96; ++c)
        acc = fmaf(cat[c], Wl1[c * D + t], acc);
    part[h][t] = acc;
    __syncthreads();
    if (tid < D) {
        float v = part[0][t] + part[1][t] + part[2][t] + part[3][t] + bl1[t];
        red[t] = fmaxf(v, 0.f) * Wl2[t];
    }
    __syncthreads();
    for (int s = 64; s > 0; s >>= 1) {
        if (tid < s) red[tid] += red[tid + s];
        __syncthreads();
    }
    if (tid == 0) out[k] = red[0] + bl2[0];
}

extern "C" void kernel_launch(void* const* d_in, const int* in_sizes, int n_in,
                              void* d_out, int out_size, void* d_ws, size_t ws_size,
                              hipStream_t stream) {
    if (ws_size < WS_NEED) return;  // safety guard

    const float* x   = (const float*)d_in[0];
    const int*   ei  = (const int*)d_in[1];   // (2,E) row-major int32
    const int*   cur = (const int*)d_in[2];
    const int*   des = (const int*)d_in[3];
    const int*   nbr = (const int*)d_in[4];
    const float* ea  = (const float*)d_in[5]; // (E,1)
    const float* We1 = (const float*)d_in[6];
    const float* be1 = (const float*)d_in[7];
    const float* W11 = (const float*)d_in[8];
    const float* b11 = (const float*)d_in[9];
    const float* W12 = (const float*)d_in[10];
    const float* b12 = (const float*)d_in[11];
    const float* We2 = (const float*)d_in[12];
    const float* be2 = (const float*)d_in[13];
    const float* W21 = (const float*)d_in[14];
    const float* b21 = (const float*)d_in[15];
    const float* W22 = (const float*)d_in[16];
    const float* b22 = (const float*)d_in[17];
    const float* Wl1 = (const float*)d_in[18];
    const float* bl1 = (const float*)d_in[19];
    const float* Wl2 = (const float*)d_in[20];
    const float* bl2 = (const float*)d_in[21];
    float* out = (float*)d_out;

    char*     ws    = (char*)d_ws;
    int*      hdr   = (int*)(ws + OFF_HDR);
    unsigned* bmS   = (unsigned*)(ws + OFF_BMS);
    float*    A1    = (float*)(ws + OFF_A1);
    int*      markS = (int*)(ws + OFF_MARKS);
    int*      Slist = (int*)(ws + OFF_SLIST);
    int*      L2    = (int*)(ws + OFF_L2);
    float*    Hs    = (float*)(ws + OFF_HS);
    float*    EMB   = (float*)(ws + OFF_EMB);

    const int* srcp = ei;
    const int* dstp = ei + Ee;

    k_zero  <<<132, 256, 0, stream>>>((float4*)ws, (int)(ZERO_BYTES / 16));
    k_scanT <<<512, 256, 0, stream>>>(srcp, dstp, cur, des, nbr,
                                      hdr, markS, bmS, Slist, L2);
    k_scanSA<<<512, 256, 0, stream>>>(x, srcp, dstp, ea, We1, be1,
                                      markS, bmS, A1);
    k_mlpS  <<<352, 512, 0, stream>>>(x, A1, Slist, hdr, W11, b11, W12, b12, Hs);
    k_tailT <<<NT, 512, 0, stream>>>(Hs, L2, hdr, markS, cur, des, nbr, ea,
                                     We2, be2, W21, b21, W22, b22, EMB);
    k_policy<<<16, 512, 0, stream>>>(EMB, cur, des, nbr, Wl1, bl1, Wl2, bl2, out);
}